// Round 3
// baseline (145.822 us; speedup 1.0000x reference)
//
#include <hip/hip_runtime.h>
#include <stdint.h>

#define MARGIN 0.3f
#define EPS 1e-12f

typedef __attribute__((ext_vector_type(8))) __bf16 bf16x8;
typedef __attribute__((ext_vector_type(4))) float f32x4;

// round-to-nearest-even fp32 -> bf16
__device__ __forceinline__ unsigned short f2bf(float f) {
    unsigned u = __float_as_uint(f);
    unsigned r = (u + 0x7FFFu + ((u >> 16) & 1u)) >> 16;
    return (unsigned short)r;
}

#define GLD16(gp, lp)                                                     \
    __builtin_amdgcn_global_load_lds(                                     \
        (const __attribute__((address_space(1))) void*)(gp),              \
        (__attribute__((address_space(3))) void*)(lp), 16, 0, 0)

// ---------------------------------------------------------------------------
// Kernel 1: fp32 -> bf16 convert, fp32 row norms, init ap/an accumulators.
// One block per row. d assumed multiple of 4*blockDim (1024 = 4*256).
// ---------------------------------------------------------------------------
__global__ __launch_bounds__(256) void prep_kernel(
    const float* __restrict__ X, unsigned short* __restrict__ Xbf,
    float* __restrict__ sqg, unsigned* __restrict__ apb,
    unsigned* __restrict__ anb, int d) {
    const int row = blockIdx.x;
    const int tid = threadIdx.x;
    const float4* Xr = (const float4*)(X + (size_t)row * d);
    float s = 0.0f;
    for (int idx = tid; idx < (d >> 2); idx += blockDim.x) {
        float4 v = Xr[idx];
        s += v.x * v.x + v.y * v.y + v.z * v.z + v.w * v.w;
        ushort4 o;
        o.x = f2bf(v.x); o.y = f2bf(v.y); o.z = f2bf(v.z); o.w = f2bf(v.w);
        ((ushort4*)(Xbf + (size_t)row * d))[idx] = o;
    }
    __shared__ float red[4];
    for (int off = 32; off > 0; off >>= 1) s += __shfl_down(s, off, 64);
    const int wave = tid >> 6, lane = tid & 63;
    if (lane == 0) red[wave] = s;
    __syncthreads();
    if (tid == 0) {
        sqg[row] = red[0] + red[1] + red[2] + red[3];
        apb[row] = 0u;            // dist >= 0, so uint compare == float compare
        anb[row] = 0x7F800000u;   // +inf
    }
}

// ---------------------------------------------------------------------------
// Kernel 2: fused Gram + distance + masked hard-mining.
// 128x128 tile, 4 waves (2x2), each wave 64x64 via 4x4 frags of 16x16x32 bf16.
// ---------------------------------------------------------------------------
#define BM 128
#define BN 128
#define BK 32

__global__ __launch_bounds__(256) void tri_gemm(
    const unsigned short* __restrict__ Xbf, const float* __restrict__ sqg,
    const int* __restrict__ tgt, unsigned* __restrict__ apb,
    unsigned* __restrict__ anb, int n, int d) {
    __shared__ unsigned short ldsA[BM * BK];
    __shared__ unsigned short ldsB[BN * BK];

    const int tid  = threadIdx.x;
    const int lane = tid & 63;
    const int wave = tid >> 6;
    const int wm = wave >> 1, wn = wave & 1;
    const int lo = lane & 15, hi = lane >> 4;
    const int rowBase = blockIdx.y * BM;
    const int colBase = blockIdx.x * BN;

    // staging decomposition: 16 chunks of 1KB (8 A + 8 B), 4 per wave
    const int lrow = lane >> 2;       // 0..15 row within 16-row chunk
    const int lk   = (lane & 3) * 8;  // bf16 k-offset 0,8,16,24

    f32x4 acc[4][4] = {};

    for (int k0 = 0; k0 < d; k0 += BK) {
#pragma unroll
        for (int c2 = 0; c2 < 2; ++c2) {
            const int c = wave * 2 + c2;
            const unsigned short* gA =
                Xbf + (size_t)(rowBase + c * 16 + lrow) * d + k0 + lk;
            GLD16(gA, &ldsA[c * 512]);
            const unsigned short* gB =
                Xbf + (size_t)(colBase + c * 16 + lrow) * d + k0 + lk;
            GLD16(gB, &ldsB[c * 512]);
        }
        asm volatile("s_waitcnt vmcnt(0)" ::: "memory");
        __syncthreads();

        bf16x8 a[4], b[4];
#pragma unroll
        for (int mi = 0; mi < 4; ++mi)
            a[mi] = *(const bf16x8*)&ldsA[(wm * 64 + mi * 16 + lo) * BK + hi * 8];
#pragma unroll
        for (int ni = 0; ni < 4; ++ni)
            b[ni] = *(const bf16x8*)&ldsB[(wn * 64 + ni * 16 + lo) * BK + hi * 8];
#pragma unroll
        for (int mi = 0; mi < 4; ++mi)
#pragma unroll
            for (int ni = 0; ni < 4; ++ni)
                acc[mi][ni] = __builtin_amdgcn_mfma_f32_16x16x32_bf16(
                    a[mi], b[ni], acc[mi][ni], 0, 0, 0);
        __syncthreads();
    }

    // epilogue: dist + mask + per-row max/min, then one atomic per row
    float sqj[4];
    int   tj[4];
#pragma unroll
    for (int ni = 0; ni < 4; ++ni) {
        const int gj = colBase + wn * 64 + ni * 16 + lo;
        sqj[ni] = sqg[gj];
        tj[ni]  = tgt[gj];
    }
#pragma unroll
    for (int mi = 0; mi < 4; ++mi) {
#pragma unroll
        for (int j = 0; j < 4; ++j) {
            const int gi = rowBase + wm * 64 + mi * 16 + hi * 4 + j;
            const float sqi = sqg[gi];
            const int   ti  = tgt[gi];
            float ap = 0.0f;
            float an = __uint_as_float(0x7F800000u);
#pragma unroll
            for (int ni = 0; ni < 4; ++ni) {
                const float d2 = sqi + sqj[ni] - 2.0f * acc[mi][ni][j];
                const float dist = sqrtf(fmaxf(d2, EPS));
                if (ti == tj[ni]) ap = fmaxf(ap, dist);
                else              an = fminf(an, dist);
            }
            // reduce across the 16 lanes (lo = 0..15) holding this row
#pragma unroll
            for (int m = 1; m < 16; m <<= 1) {
                ap = fmaxf(ap, __shfl_xor(ap, m, 64));
                an = fminf(an, __shfl_xor(an, m, 64));
            }
            if (lo == 0) {
                atomicMax(&apb[gi], __float_as_uint(ap));
                atomicMin(&anb[gi], __float_as_uint(an));
            }
        }
    }
}

// ---------------------------------------------------------------------------
// Kernel 3: loss + precision
// ---------------------------------------------------------------------------
__global__ __launch_bounds__(256) void finalize_kernel(
    const unsigned* __restrict__ apb, const unsigned* __restrict__ anb,
    float* __restrict__ out, int n) {
    const int tid = threadIdx.x;
    float ls = 0.0f, pc = 0.0f;
    for (int i = tid; i < n; i += blockDim.x) {
        const float ap = __uint_as_float(apb[i]);
        const float an = __uint_as_float(anb[i]);
        ls += fmaxf(MARGIN - (an - ap), 0.0f);
        pc += (an > ap) ? 1.0f : 0.0f;
    }
    __shared__ float rl[4], rp[4];
    for (int off = 32; off > 0; off >>= 1) {
        ls += __shfl_down(ls, off, 64);
        pc += __shfl_down(pc, off, 64);
    }
    const int wave = tid >> 6, lane = tid & 63;
    if (lane == 0) { rl[wave] = ls; rp[wave] = pc; }
    __syncthreads();
    if (tid == 0) {
        out[0] = (rl[0] + rl[1] + rl[2] + rl[3]) / (float)n;
        out[1] = (rp[0] + rp[1] + rp[2] + rp[3]) / (float)n;
    }
}

// ---------------------------------------------------------------------------
// Fallback path (only if ws_size is too small for the bf16 matrix): pure
// fp32, zero workspace. One block per row i; diff-square distances.
// ---------------------------------------------------------------------------
__global__ __launch_bounds__(256) void fb_zero(float* __restrict__ out) {
    if (threadIdx.x == 0) { out[0] = 0.0f; out[1] = 0.0f; }
}

__global__ __launch_bounds__(256) void fb_row(
    const float* __restrict__ X, const int* __restrict__ tgt,
    float* __restrict__ out, int n, int d) {
    __shared__ float xi[4096];  // supports d <= 4096
    const int i = blockIdx.x;
    const int tid = threadIdx.x;
    for (int k = tid; k < d; k += 256) xi[k] = X[(size_t)i * d + k];
    __syncthreads();
    const int ti = tgt[i];
    float ap = 0.0f;
    float an = __uint_as_float(0x7F800000u);
    for (int j = tid; j < n; j += 256) {
        const float4* Xj = (const float4*)(X + (size_t)j * d);
        float s = 0.0f;
        for (int k4 = 0; k4 < (d >> 2); ++k4) {
            float4 v = Xj[k4];
            float4 u = *(const float4*)&xi[k4 * 4];
            float dx = u.x - v.x, dy = u.y - v.y, dz = u.z - v.z, dw = u.w - v.w;
            s += dx * dx + dy * dy + dz * dz + dw * dw;
        }
        const float dist = sqrtf(fmaxf(s, EPS));
        if (tgt[j] == ti) ap = fmaxf(ap, dist);
        else              an = fminf(an, dist);
    }
    for (int m = 1; m < 64; m <<= 1) {
        ap = fmaxf(ap, __shfl_xor(ap, m, 64));
        an = fminf(an, __shfl_xor(an, m, 64));
    }
    __shared__ float rap[4], ran[4];
    const int wave = tid >> 6, lane = tid & 63;
    if (lane == 0) { rap[wave] = ap; ran[wave] = an; }
    __syncthreads();
    if (tid == 0) {
        ap = fmaxf(fmaxf(rap[0], rap[1]), fmaxf(rap[2], rap[3]));
        an = fminf(fminf(ran[0], ran[1]), fminf(ran[2], ran[3]));
        atomicAdd(&out[0], fmaxf(MARGIN - (an - ap), 0.0f));
        atomicAdd(&out[1], (an > ap) ? 1.0f : 0.0f);
    }
}

__global__ __launch_bounds__(64) void fb_scale(float* __restrict__ out, float inv_n) {
    if (threadIdx.x == 0) { out[0] *= inv_n; out[1] *= inv_n; }
}

// ---------------------------------------------------------------------------
extern "C" void kernel_launch(void* const* d_in, const int* in_sizes, int n_in,
                              void* d_out, int out_size, void* d_ws, size_t ws_size,
                              hipStream_t stream) {
    const float* X   = (const float*)d_in[0];
    const int*   tgt = (const int*)d_in[1];
    const int n = in_sizes[1];
    const int d = in_sizes[0] / n;

    const size_t need = (size_t)n * d * 2 + (size_t)n * 4 * 3;
    if (ws_size >= need) {
        char* ws = (char*)d_ws;
        unsigned short* Xbf = (unsigned short*)ws;                 // n*d*2 B
        float*    sqg = (float*)(ws + (size_t)n * d * 2);          // n*4 B
        unsigned* apb = (unsigned*)((char*)sqg + (size_t)n * 4);   // n*4 B
        unsigned* anb = apb + n;                                   // n*4 B

        prep_kernel<<<n, 256, 0, stream>>>(X, Xbf, sqg, apb, anb, d);
        dim3 grid(n / BN, n / BM);
        tri_gemm<<<grid, 256, 0, stream>>>(Xbf, sqg, tgt, apb, anb, n, d);
        finalize_kernel<<<1, 256, 0, stream>>>(apb, anb, (float*)d_out, n);
    } else {
        fb_zero<<<1, 256, 0, stream>>>((float*)d_out);
        fb_row<<<n, 256, 0, stream>>>(X, tgt, (float*)d_out, n, d);
        fb_scale<<<1, 64, 0, stream>>>((float*)d_out, 1.0f / (float)n);
    }
}